// Round 2
// baseline (65.199 us; speedup 1.0000x reference)
//
#include <hip/hip_runtime.h>
#include <cstdint>
#include <cstddef>

#define S      4096   // N == M
#define BATCH  16
#define BLK    256
#define P      8                     // outer points per thread
#define OUTER_PER_BLK (BLK * P)      // 2048
#define IS     16                    // inner split
#define MC     (S / IS)              // 256 inner points staged in LDS (4 KB)

// ---------------------------------------------------------------------------
// Pass 1: for each (role, b, outer point) compute min over an inner chunk of
//   t = |inner|^2/2 - outer . inner          (3 FMA + 1 min per pair)
// then dist^2 = 2*t + |outer|^2, combined across inner-split blocks via
// atomicMin on the uint bit pattern (valid: dist^2 clamped >= 0).
// grid = (OC * IS, BATCH, 2); role 0: outer=x inner=y, role 1: swap.
// ---------------------------------------------------------------------------
__global__ __launch_bounds__(BLK) void chamfer_min_kernel(
    const float* __restrict__ x, const float* __restrict__ y,
    unsigned int* __restrict__ wsmin)
{
    const int role = blockIdx.z;
    const int b    = blockIdx.y;
    const int ic   = blockIdx.x & (IS - 1);
    const int oc   = blockIdx.x >> 4;          // / IS
    const float* __restrict__ outer = (role == 0) ? x : y;
    const float* __restrict__ inner = (role == 0) ? y : x;

    const int tid     = threadIdx.x;
    const int n0      = oc * OUTER_PER_BLK;
    const int m_begin = ic * MC;

    __shared__ float4 lds[MC];

    // Stage the inner chunk: 256 threads, 256 points -> single pass.
    {
        const float* yp = inner + ((size_t)b * S + m_begin + tid) * 3;
        const float a0 = yp[0], a1 = yp[1], a2 = yp[2];
        lds[tid] = make_float4(a0, a1, a2,
                               0.5f * (a0 * a0 + a1 * a1 + a2 * a2));
    }

    // This thread's P outer points in registers (negated for FMA form).
    float nx0[P], nx1[P], nx2[P], xn[P], tmin[P];
#pragma unroll
    for (int p = 0; p < P; ++p) {
        const int n = n0 + p * BLK + tid;
        const float* xp = outer + ((size_t)b * S + n) * 3;
        const float a0 = xp[0], a1 = xp[1], a2 = xp[2];
        nx0[p] = -a0; nx1[p] = -a1; nx2[p] = -a2;
        xn[p]  = a0 * a0 + a1 * a1 + a2 * a2;
        tmin[p] = 3.0e38f;
    }

    __syncthreads();

    // Inner loop, software-pipelined: keep the next LDS read in flight.
    float4 v = lds[0];
#pragma unroll 4
    for (int j = 0; j < MC - 1; ++j) {
        const float4 vn = lds[j + 1];
#pragma unroll
        for (int p = 0; p < P; ++p) {
            const float t = fmaf(nx0[p], v.x,
                             fmaf(nx1[p], v.y,
                              fmaf(nx2[p], v.z, v.w)));
            tmin[p] = fminf(tmin[p], t);
        }
        v = vn;
    }
#pragma unroll
    for (int p = 0; p < P; ++p) {
        const float t = fmaf(nx0[p], v.x,
                         fmaf(nx1[p], v.y,
                          fmaf(nx2[p], v.z, v.w)));
        tmin[p] = fminf(tmin[p], t);
    }

    unsigned int* wm = wsmin + ((size_t)role * BATCH + b) * S;
#pragma unroll
    for (int p = 0; p < P; ++p) {
        const int n = n0 + p * BLK + tid;
        const float val = fmaxf(fmaf(2.0f, tmin[p], xn[p]), 0.0f); // dist^2 >= 0
        atomicMin(&wm[n], __float_as_uint(val));
    }
}

// ---------------------------------------------------------------------------
// Pass 2: per batch, mean of sqrt(min dist^2) over both directions.
// Deterministic fixed-order block reduction; writes d_out[b] directly.
// ---------------------------------------------------------------------------
__global__ __launch_bounds__(BLK) void chamfer_reduce_kernel(
    const unsigned int* __restrict__ wsmin, float* __restrict__ out)
{
    const int b = blockIdx.x;
    const int tid = threadIdx.x;
    const unsigned int* w0 = wsmin + (size_t)b * S;
    const unsigned int* w1 = wsmin + (size_t)(BATCH + b) * S;

    float s = 0.0f;
    for (int i = tid; i < S; i += BLK) {
        s += sqrtf(__uint_as_float(w0[i])) + sqrtf(__uint_as_float(w1[i]));
    }

    __shared__ float red[BLK];
    red[tid] = s;
    __syncthreads();
    for (int off = BLK / 2; off > 0; off >>= 1) {
        if (tid < off) red[tid] += red[tid + off];
        __syncthreads();
    }
    if (tid == 0) out[b] = red[0] * (0.5f / (float)S);
}

// ---------------------------------------------------------------------------
// Fallback (no workspace): each block covers the FULL inner range for its
// outer points, then atomicAdd of the partial sqrt-sum into d_out.
// ---------------------------------------------------------------------------
#define FMC 1024
__global__ __launch_bounds__(BLK) void chamfer_full_kernel(
    const float* __restrict__ x, const float* __restrict__ y,
    float* __restrict__ out)
{
    const int role = blockIdx.z;
    const int b    = blockIdx.y;
    const int oc   = blockIdx.x;
    const float* __restrict__ outer = (role == 0) ? x : y;
    const float* __restrict__ inner = (role == 0) ? y : x;
    const int tid = threadIdx.x;
    const int n0  = oc * OUTER_PER_BLK;

    __shared__ float4 lds[FMC];

    float nx0[P], nx1[P], nx2[P], xn[P], tmin[P];
#pragma unroll
    for (int p = 0; p < P; ++p) {
        const int n = n0 + p * BLK + tid;
        const float* xp = outer + ((size_t)b * S + n) * 3;
        const float a0 = xp[0], a1 = xp[1], a2 = xp[2];
        nx0[p] = -a0; nx1[p] = -a1; nx2[p] = -a2;
        xn[p]  = a0 * a0 + a1 * a1 + a2 * a2;
        tmin[p] = 3.0e38f;
    }

    for (int m0 = 0; m0 < S; m0 += FMC) {
        __syncthreads();
        for (int i = tid; i < FMC; i += BLK) {
            const float* yp = inner + ((size_t)b * S + m0 + i) * 3;
            const float a0 = yp[0], a1 = yp[1], a2 = yp[2];
            lds[i] = make_float4(a0, a1, a2,
                                 0.5f * (a0 * a0 + a1 * a1 + a2 * a2));
        }
        __syncthreads();
#pragma unroll 4
        for (int j = 0; j < FMC; ++j) {
            const float4 v = lds[j];
#pragma unroll
            for (int p = 0; p < P; ++p) {
                const float t = fmaf(nx0[p], v.x,
                                 fmaf(nx1[p], v.y,
                                  fmaf(nx2[p], v.z, v.w)));
                tmin[p] = fminf(tmin[p], t);
            }
        }
    }

    float s = 0.0f;
#pragma unroll
    for (int p = 0; p < P; ++p) {
        s += sqrtf(fmaxf(fmaf(2.0f, tmin[p], xn[p]), 0.0f));
    }

    __shared__ float red[BLK];
    red[tid] = s;
    __syncthreads();
    for (int off = BLK / 2; off > 0; off >>= 1) {
        if (tid < off) red[tid] += red[tid + off];
        __syncthreads();
    }
    if (tid == 0) atomicAdd(&out[b], red[0] * (0.5f / (float)S));
}

extern "C" void kernel_launch(void* const* d_in, const int* in_sizes, int n_in,
                              void* d_out, int out_size, void* d_ws, size_t ws_size,
                              hipStream_t stream) {
    const float* x = (const float*)d_in[0];
    const float* y = (const float*)d_in[1];
    float* out = (float*)d_out;

    const size_t need = (size_t)2 * BATCH * S * sizeof(float);  // 512 KB
    if (ws_size >= need) {
        // 0x7F7F7F7F == 3.39e38f: larger than any real dist^2 -> valid +inf proxy.
        hipMemsetAsync(d_ws, 0x7F, need, stream);
        const int OC = S / OUTER_PER_BLK;      // 2
        chamfer_min_kernel<<<dim3(OC * IS, BATCH, 2), BLK, 0, stream>>>(
            x, y, (unsigned int*)d_ws);
        chamfer_reduce_kernel<<<BATCH, BLK, 0, stream>>>(
            (const unsigned int*)d_ws, out);
    } else {
        hipMemsetAsync(d_out, 0, BATCH * sizeof(float), stream);
        chamfer_full_kernel<<<dim3(S / OUTER_PER_BLK, BATCH, 2), BLK, 0, stream>>>(
            x, y, out);
    }
}

// Round 3
// 46.775 us; speedup vs baseline: 1.3939x; 1.3939x over previous
//
#include <hip/hip_runtime.h>
#include <cstdint>
#include <cstddef>

#define S      4096
#define BATCH  16
#define BLK    256
#define YSPAN  2048                 // y range per block (z-dim splits S into 2)
#define CHUNK  512                  // y points staged per chunk
#define NTILE  (CHUNK / 32)         // 16 tiles of 32 y-points
#define NCHUNK (YSPAN / CHUNK)      // 4
#define ROWS_PER_BLOCK 128          // 4 waves x 32 rows

typedef _Float16 half8   __attribute__((ext_vector_type(8)));
typedef float    floatx16 __attribute__((ext_vector_type(16)));

__device__ inline unsigned pack2(_Float16 lo, _Float16 hi) {
    unsigned short a = __builtin_bit_cast(unsigned short, lo);
    unsigned short b = __builtin_bit_cast(unsigned short, hi);
    return (unsigned)a | ((unsigned)b << 16);
}

// ---------------------------------------------------------------------------
// One MFMA per 32x32 tile computes D = d^2/2 for 1024 pairs:
//   A lanes 0-31  (k0-7):  [-xh0,-xh1,-xh2, -xh0,-xh1,-xh2, -xl0,-xl1]
//   A lanes 32-63 (k8-15): [-xl2, 1, 1, xnh, xnl, 0, 0, 0]
//   B lanes 0-31  (k0-7):  [yh0,yh1,yh2, yl0,yl1,yl2, yh0,yh1]
//   B lanes 32-63 (k8-15): [yh2, hh, hl, 1, 1, 0, 0, 0]
// where *h/*l = f16 hi/lo split, h = |y|^2/2, xn = |x|^2/2.
// D[k] sum = xn + h - x.y  (error ~1e-6).  C/D: col=lane&31,
// row=(reg&3)+8*(reg>>2)+4*(lane>>5).
// ---------------------------------------------------------------------------
__global__ __launch_bounds__(BLK) void chamfer_mfma_kernel(
    const float* __restrict__ x, const float* __restrict__ y,
    unsigned* __restrict__ ws0, unsigned* __restrict__ ws1)
{
    const int b    = blockIdx.y;
    const int xc   = blockIdx.x;          // 0..31
    const int yc   = blockIdx.z;          // 0..1
    const int tid  = threadIdx.x;
    const int lane = tid & 63;
    const int wave = tid >> 6;            // 0..3
    const int hi32 = lane >> 5;
    const int l31  = lane & 31;

    __shared__ uint4   ldsb[2][NTILE][64];
    __shared__ unsigned colmin[YSPAN];

    for (int i = tid; i < YSPAN; i += BLK) colmin[i] = 0x7F7F7F7Fu;
    // constant .z/.w of the upper-lane B slots: [e4=1, e5..7=0]
    for (int i = tid; i < 2 * NTILE * 32; i += BLK) {
        int bu = i / (NTILE * 32); int r = i % (NTILE * 32);
        ldsb[bu][r >> 5][32 + (r & 31)].z = 0x00003C00u;  // pack(1.0h, 0h)
        ldsb[bu][r >> 5][32 + (r & 31)].w = 0u;
    }

    // ---- A fragment (this wave's 32 x-rows; both lane-halves load same row)
    const int row = xc * ROWS_PER_BLOCK + wave * 32 + l31;
    const float* xp = x + ((size_t)b * S + row) * 3;
    const float x0 = xp[0], x1 = xp[1], x2 = xp[2];
    const float xn = 0.5f * (x0 * x0 + x1 * x1 + x2 * x2);
    const _Float16 xh0 = (_Float16)x0, xh1 = (_Float16)x1, xh2 = (_Float16)x2;
    const _Float16 xl0 = (_Float16)(x0 - (float)xh0);
    const _Float16 xl1 = (_Float16)(x1 - (float)xh1);
    const _Float16 xl2 = (_Float16)(x2 - (float)xh2);
    const _Float16 xnh = (_Float16)xn;
    const _Float16 xnl = (_Float16)(xn - (float)xnh);
    half8 afrag;
    if (hi32 == 0) {
        afrag[0] = -xh0; afrag[1] = -xh1; afrag[2] = -xh2;
        afrag[3] = -xh0; afrag[4] = -xh1; afrag[5] = -xh2;
        afrag[6] = -xl0; afrag[7] = -xl1;
    } else {
        afrag[0] = -xl2; afrag[1] = (_Float16)1.0f; afrag[2] = (_Float16)1.0f;
        afrag[3] = xnh;  afrag[4] = xnl;
        afrag[5] = (_Float16)0.0f; afrag[6] = (_Float16)0.0f; afrag[7] = (_Float16)0.0f;
    }

    floatx16 runrow;
#pragma unroll
    for (int r = 0; r < 16; ++r) runrow[r] = 3.0e38f;
    const floatx16 zeroacc = {};

    const int ybase = yc * YSPAN;
    const float* ysrc = y + ((size_t)b * S + ybase) * 3;

    auto stage = [&](int cc) {
        const int buf = cc & 1;
#pragma unroll
        for (int q = 0; q < 2; ++q) {
            const int pl = tid * 2 + q;            // 0..CHUNK
            const int p  = cc * CHUNK + pl;        // within YSPAN
            const float* yp = ysrc + (size_t)p * 3;
            const float y0 = yp[0], y1 = yp[1], y2 = yp[2];
            const float h  = 0.5f * (y0 * y0 + y1 * y1 + y2 * y2);
            const _Float16 a0 = (_Float16)y0, a1 = (_Float16)y1, a2 = (_Float16)y2;
            const _Float16 b0 = (_Float16)(y0 - (float)a0);
            const _Float16 b1 = (_Float16)(y1 - (float)a1);
            const _Float16 b2 = (_Float16)(y2 - (float)a2);
            const _Float16 hh = (_Float16)h;
            const _Float16 hl = (_Float16)(h - (float)hh);
            const int t = pl >> 5, col = pl & 31;
            ldsb[buf][t][col] = make_uint4(pack2(a0, a1), pack2(a2, b0),
                                           pack2(b1, b2), pack2(a0, a1));
            *(uint2*)&ldsb[buf][t][32 + col] =
                make_uint2(pack2(a2, hh), pack2(hl, (_Float16)1.0f));
        }
    };

    stage(0);
    __syncthreads();

    for (int c = 0; c < NCHUNK; ++c) {
        if (c + 1 < NCHUNK) stage(c + 1);
        const int buf = c & 1;
#pragma unroll 4
        for (int t = 0; t < NTILE; ++t) {
            const uint4 braw = ldsb[buf][t][lane];
            const half8 bfrag = __builtin_bit_cast(half8, braw);
            const floatx16 d =
                __builtin_amdgcn_mfma_f32_32x32x16_f16(afrag, bfrag, zeroacc, 0, 0, 0);
            // x-direction: running row mins (16 rows per lane)
#pragma unroll
            for (int r = 0; r < 16; ++r) runrow[r] = fminf(runrow[r], d[r]);
            // y-direction: fold 16 regs (min3-fusable chains), then lane-halves
            float m = fminf(fminf(d[0], d[1]), d[2]);
            m = fminf(fminf(m, d[3]), d[4]);
            m = fminf(fminf(m, d[5]), d[6]);
            m = fminf(fminf(m, d[7]), d[8]);
            m = fminf(fminf(m, d[9]), d[10]);
            m = fminf(fminf(m, d[11]), d[12]);
            m = fminf(fminf(m, d[13]), d[14]);
            m = fminf(m, d[15]);
            m = fminf(m, __shfl_xor(m, 32));
            m = fmaxf(m, 0.0f);
            if (lane < 32)
                atomicMin(&colmin[c * CHUNK + t * 32 + l31], __float_as_uint(m));
        }
        __syncthreads();
    }

    // ---- x-direction flush: butterfly over the 32 cols, then store rows
#pragma unroll
    for (int r = 0; r < 16; ++r) {
        float v = runrow[r];
        v = fminf(v, __shfl_xor(v, 1));
        v = fminf(v, __shfl_xor(v, 2));
        v = fminf(v, __shfl_xor(v, 4));
        v = fminf(v, __shfl_xor(v, 8));
        v = fminf(v, __shfl_xor(v, 16));
        runrow[r] = v;
    }
    if (l31 == 0) {
        unsigned* w0 = ws0 + (size_t)b * S + xc * ROWS_PER_BLOCK + wave * 32;
#pragma unroll
        for (int r = 0; r < 16; ++r) {
            const int rr = (r & 3) + 8 * (r >> 2) + 4 * hi32;
            atomicMin(&w0[rr], __float_as_uint(fmaxf(runrow[r], 0.0f)));
        }
    }

    // ---- y-direction flush (loop-end barrier already synced all ds_mins)
    unsigned* w1 = ws1 + (size_t)b * S + ybase;
    for (int i = tid; i < YSPAN; i += BLK) atomicMin(&w1[i], colmin[i]);
}

// ---------------------------------------------------------------------------
// Pass 2: per batch, mean of sqrt(2 * d^2/2) over both directions.
// ---------------------------------------------------------------------------
__global__ __launch_bounds__(BLK) void chamfer_reduce_kernel(
    const unsigned* __restrict__ ws0, const unsigned* __restrict__ ws1,
    float* __restrict__ out)
{
    const int b = blockIdx.x;
    const int tid = threadIdx.x;
    float s = 0.0f;
    for (int i = tid; i < S; i += BLK) {
        s += sqrtf(2.0f * __uint_as_float(ws0[(size_t)b * S + i]))
           + sqrtf(2.0f * __uint_as_float(ws1[(size_t)b * S + i]));
    }
    __shared__ float red[BLK];
    red[tid] = s;
    __syncthreads();
    for (int off = BLK / 2; off > 0; off >>= 1) {
        if (tid < off) red[tid] += red[tid + off];
        __syncthreads();
    }
    if (tid == 0) out[b] = red[0] * (0.5f / (float)S);
}

// ---------------------------------------------------------------------------
// Fallback (no workspace): scalar full-range kernel, atomicAdd into out.
// ---------------------------------------------------------------------------
#define P   8
#define FMC 1024
#define OUTER_PER_BLK (BLK * P)
__global__ __launch_bounds__(BLK) void chamfer_full_kernel(
    const float* __restrict__ x, const float* __restrict__ y,
    float* __restrict__ out)
{
    const int role = blockIdx.z;
    const int b    = blockIdx.y;
    const int oc   = blockIdx.x;
    const float* __restrict__ outer = (role == 0) ? x : y;
    const float* __restrict__ inner = (role == 0) ? y : x;
    const int tid = threadIdx.x;
    const int n0  = oc * OUTER_PER_BLK;

    __shared__ float4 lds[FMC];

    float nx0[P], nx1[P], nx2[P], xn[P], tmin[P];
#pragma unroll
    for (int p = 0; p < P; ++p) {
        const int n = n0 + p * BLK + tid;
        const float* xp = outer + ((size_t)b * S + n) * 3;
        const float a0 = xp[0], a1 = xp[1], a2 = xp[2];
        nx0[p] = -a0; nx1[p] = -a1; nx2[p] = -a2;
        xn[p]  = a0 * a0 + a1 * a1 + a2 * a2;
        tmin[p] = 3.0e38f;
    }

    for (int m0 = 0; m0 < S; m0 += FMC) {
        __syncthreads();
        for (int i = tid; i < FMC; i += BLK) {
            const float* yp = inner + ((size_t)b * S + m0 + i) * 3;
            const float a0 = yp[0], a1 = yp[1], a2 = yp[2];
            lds[i] = make_float4(a0, a1, a2,
                                 0.5f * (a0 * a0 + a1 * a1 + a2 * a2));
        }
        __syncthreads();
#pragma unroll 4
        for (int j = 0; j < FMC; ++j) {
            const float4 v = lds[j];
#pragma unroll
            for (int p = 0; p < P; ++p) {
                const float t = fmaf(nx0[p], v.x,
                                 fmaf(nx1[p], v.y,
                                  fmaf(nx2[p], v.z, v.w)));
                tmin[p] = fminf(tmin[p], t);
            }
        }
    }

    float s = 0.0f;
#pragma unroll
    for (int p = 0; p < P; ++p)
        s += sqrtf(fmaxf(fmaf(2.0f, tmin[p], xn[p]), 0.0f));

    __shared__ float red[BLK];
    red[tid] = s;
    __syncthreads();
    for (int off = BLK / 2; off > 0; off >>= 1) {
        if (tid < off) red[tid] += red[tid + off];
        __syncthreads();
    }
    if (tid == 0) atomicAdd(&out[b], red[0] * (0.5f / (float)S));
}

extern "C" void kernel_launch(void* const* d_in, const int* in_sizes, int n_in,
                              void* d_out, int out_size, void* d_ws, size_t ws_size,
                              hipStream_t stream) {
    const float* x = (const float*)d_in[0];
    const float* y = (const float*)d_in[1];
    float* out = (float*)d_out;

    const size_t need = (size_t)2 * BATCH * S * sizeof(unsigned);  // 512 KB
    if (ws_size >= need) {
        unsigned* ws0 = (unsigned*)d_ws;
        unsigned* ws1 = ws0 + (size_t)BATCH * S;
        // 0x7F7F7F7F: huge positive float, also huge uint -> +inf proxy.
        hipMemsetAsync(d_ws, 0x7F, need, stream);
        chamfer_mfma_kernel<<<dim3(S / ROWS_PER_BLOCK, BATCH, S / YSPAN),
                              BLK, 0, stream>>>(x, y, ws0, ws1);
        chamfer_reduce_kernel<<<BATCH, BLK, 0, stream>>>(ws0, ws1, out);
    } else {
        hipMemsetAsync(d_out, 0, BATCH * sizeof(float), stream);
        chamfer_full_kernel<<<dim3(S / OUTER_PER_BLK, BATCH, 2), BLK, 0, stream>>>(
            x, y, out);
    }
}